// Round 8
// baseline (151.893 us; speedup 1.0000x reference)
//
#include <hip/hip_runtime.h>

typedef _Float16 f16;
typedef __attribute__((ext_vector_type(2))) _Float16 f16x2;
typedef __attribute__((ext_vector_type(8))) _Float16 f16x8;
typedef __attribute__((ext_vector_type(4))) float f32x4;

#define MFMA16(a,b,c) __builtin_amdgcn_mfma_f32_16x16x32_f16(a,b,c,0,0,0)

constexpr int NSEQ = 64;    // 2*8*4
constexpr int P    = 256;   // tokens per sequence
constexpr int DIMF = 768;
constexpr int NH   = 12;
constexpr int DH   = 64;
constexpr int M    = NSEQ * P;        // 16384
constexpr size_t XSZ = (size_t)M * DIMF;
constexpr size_t WSZ = (size_t)DIMF * DIMF;

__device__ __forceinline__ f16x8 cvt8(const float* p) {
    const float4 u = *(const float4*)p;
    const float4 w = *(const float4*)(p + 4);
    f16x2 a = __builtin_bit_cast(f16x2, __builtin_amdgcn_cvt_pkrtz(u.x, u.y));
    f16x2 b = __builtin_bit_cast(f16x2, __builtin_amdgcn_cvt_pkrtz(u.z, u.w));
    f16x2 c = __builtin_bit_cast(f16x2, __builtin_amdgcn_cvt_pkrtz(w.x, w.y));
    f16x2 d = __builtin_bit_cast(f16x2, __builtin_amdgcn_cvt_pkrtz(w.z, w.w));
    f16x8 r;
    r[0]=a[0]; r[1]=a[1]; r[2]=b[0]; r[3]=b[1];
    r[4]=c[0]; r[5]=c[1]; r[6]=d[0]; r[7]=d[1];
    return r;
}

__device__ __forceinline__ void gload16(const void* g, void* l) {
    __builtin_amdgcn_global_load_lds(
        (const __attribute__((address_space(1))) void*)g,
        (__attribute__((address_space(3))) void*)l, 16, 0, 0);
}

// ---- fp32 -> fp16 convert ----
__global__ __launch_bounds__(256) void conv_kernel(
    const float* __restrict__ x,
    const float* __restrict__ Wq, const float* __restrict__ Wk,
    const float* __restrict__ Wv,
    f16* __restrict__ xh, f16* __restrict__ wh)
{
    const size_t i8 = ((size_t)blockIdx.x * 256 + threadIdx.x) * 8;
    if (i8 < XSZ) {
        *(f16x8*)(xh + i8) = cvt8(x + i8);
    } else {
        const size_t j = i8 - XSZ;
        const int mtx = (int)(j / WSZ);
        const size_t r = j - (size_t)mtx * WSZ;
        const float* src = (mtx == 0 ? Wq : mtx == 1 ? Wk : Wv) + r;
        *(f16x8*)(wh + j) = cvt8(src);
    }
}

// ---- projection GEMM: 256x256 tile, BK=32, QUAD-buffered LDS (4 x 32KB),
// staging lead = 2 K-tiles, vmcnt(6) once per tile (counted, never 0 in loop).
// 8 waves: wave (wm,wn) owns rows wm*128..+128 x cols wn*64..+64.
// LDS: A bufs q*16384 at 0; B bufs at 65536. Chunk-swizzle c ^= row&3.
__global__ __launch_bounds__(512, 1) void proj_gemm(
    const f16* __restrict__ xh, const f16* __restrict__ wh,
    const float* __restrict__ bq, const float* __restrict__ bk,
    const float* __restrict__ bv,
    f16* __restrict__ qout, f16* __restrict__ kout, f16* __restrict__ vt)
{
    __shared__ __align__(16) char smem[131072];
    const int tid  = threadIdx.x;
    const int lane = tid & 63;
    const int wave = tid >> 6;
    const int lr   = lane & 15;
    const int lg   = lane >> 4;
    const int wm   = wave >> 2;       // 0..1 : 128-row half
    const int wn   = wave & 3;        // 0..3 : 64-col strip

    const int swz   = (lg ^ (lr & 3)) * 16;
    const int rAoff = (wm * 128 + lr) * 64 + swz;            // + q*16384 + m*1024
    const int rBoff = 65536 + (wn * 64 + lr) * 64 + swz;     // + q*16384 + n*1024

    const int wg0 = (blockIdx.x & 7) * 64 + (blockIdx.x >> 3);   // bijective on 512

    #define BAR  __builtin_amdgcn_s_barrier()
    #define LGKM asm volatile("s_waitcnt lgkmcnt(0)" ::: "memory")
    #define SCHB __builtin_amdgcn_sched_barrier(0)

    for (int wg = wg0; wg < 576; wg += 512) {
        const int nt = wg % 9;
        const int mt = wg / 9;
        const int m0 = mt * 256, n0 = nt * 256;

        // per-thread staging source (chunk-swizzled), row = tid>>2, chunk = tid&3
        const f16* srcA = xh + (size_t)(m0 + (tid >> 2)) * DIMF
                             + (((tid & 3) ^ ((tid >> 2) & 3)) * 8);
        const f16* srcB = wh + (size_t)(n0 + (tid >> 2)) * DIMF
                             + (((tid & 3) ^ ((tid >> 2) & 3)) * 8);

        f32x4 acc[8][4];
        #pragma unroll
        for (int m = 0; m < 8; ++m)
            #pragma unroll
            for (int n = 0; n < 4; ++n) acc[m][n] = (f32x4){0.f,0.f,0.f,0.f};

        // prologue: stage tiles 0,1 (A0,A1,B0,B1 each)
        #pragma unroll
        for (int t0 = 0; t0 < 2; ++t0) {
            gload16(srcA + t0*32,                      smem + t0*16384 + tid*16);
            gload16(srcA + t0*32 + (size_t)128*DIMF,   smem + t0*16384 + 8192 + tid*16);
            gload16(srcB + t0*32,                      smem + 65536 + t0*16384 + tid*16);
            gload16(srcB + t0*32 + (size_t)128*DIMF,   smem + 65536 + t0*16384 + 8192 + tid*16);
        }
        asm volatile("s_waitcnt vmcnt(4)" ::: "memory");
        BAR;

        f16x8 a[4], bb[4];

        #define PH0(QO, STG, VMW)                                              \
            _Pragma("unroll")                                                  \
            for (int m = 0; m < 4; ++m)                                        \
                a[m] = *(const f16x8*)(smem + (QO) + rAoff + m*1024);          \
            _Pragma("unroll")                                                  \
            for (int n = 0; n < 4; ++n)                                        \
                bb[n] = *(const f16x8*)(smem + (QO) + rBoff + n*1024);         \
            STG;                                                               \
            VMW;                                                               \
            BAR; LGKM; SCHB;                                                   \
            __builtin_amdgcn_s_setprio(1);                                     \
            _Pragma("unroll")                                                  \
            for (int m = 0; m < 4; ++m)                                        \
                _Pragma("unroll")                                              \
                for (int n = 0; n < 4; ++n)                                    \
                    acc[m][n] = MFMA16(a[m], bb[n], acc[m][n]);                \
            __builtin_amdgcn_s_setprio(0);

        #define PH1(QO, STG)                                                   \
            _Pragma("unroll")                                                  \
            for (int m = 0; m < 4; ++m)                                        \
                a[m] = *(const f16x8*)(smem + (QO) + rAoff + (4+m)*1024);      \
            STG;                                                               \
            BAR; LGKM; SCHB;                                                   \
            __builtin_amdgcn_s_setprio(1);                                     \
            _Pragma("unroll")                                                  \
            for (int m = 0; m < 4; ++m)                                        \
                _Pragma("unroll")                                              \
                for (int n = 0; n < 4; ++n)                                    \
                    acc[4+m][n] = MFMA16(a[m], bb[n], acc[4+m][n]);            \
            __builtin_amdgcn_s_setprio(0);

        // main loop: tiles 0..21, staging tile T+2, vmcnt(6) once per tile
        for (int T = 0; T < 22; ++T) {
            const int qo = (T & 3) * 16384;
            const int so = ((T + 2) & 3) * 16384;
            const f16* ga = srcA + (size_t)(T + 2) * 32;
            const f16* gb = srcB + (size_t)(T + 2) * 32;
            PH0(qo,
                { gload16(ga, smem + so + tid*16);
                  gload16(ga + (size_t)128*DIMF, smem + so + 8192 + tid*16); },
                asm volatile("s_waitcnt vmcnt(6)" ::: "memory"));
            PH1(qo,
                { gload16(gb, smem + 65536 + so + tid*16);
                  gload16(gb + (size_t)128*DIMF, smem + 65536 + so + 8192 + tid*16); });
        }
        // tile 22: no staging; need tile 22's units done -> vmcnt(4)
        PH0(2*16384, {}, asm volatile("s_waitcnt vmcnt(4)" ::: "memory"));
        PH1(2*16384, {});
        // tile 23: drain
        PH0(3*16384, {}, asm volatile("s_waitcnt vmcnt(0)" ::: "memory"));
        PH1(3*16384, {});

        #undef PH0
        #undef PH1

        __syncthreads();

        // ---- epilogue: 2-pass LDS bounce (pass hh = 128-row half) ----
        const int mat = nt / 3;               // 0=q 1=k 2=v
        const int c0  = (nt % 3) * 256;
        const int seq = mt;
        const float* __restrict__ bias = mat == 0 ? bq : mat == 1 ? bk : bv;
        float bv4[4];
        #pragma unroll
        for (int n = 0; n < 4; ++n) bv4[n] = bias[c0 + wn*64 + n*16 + lr];

        f16 (*ep)[264] = (f16 (*)[264])smem;
        #pragma unroll
        for (int hh = 0; hh < 2; ++hh) {
            if (wm == hh) {
                #pragma unroll
                for (int m = 0; m < 8; ++m)
                    #pragma unroll
                    for (int n = 0; n < 4; ++n)
                        #pragma unroll
                        for (int i = 0; i < 4; ++i)
                            ep[m*16 + lg*4 + i][wn*64 + n*16 + lr] =
                                (f16)(acc[m][n][i] + bv4[n]);
            }
            __syncthreads();
            if (mat < 2) {
                f16* __restrict__ dst = mat ? kout : qout;
                const int r = tid >> 2;
                #pragma unroll
                for (int s = 0; s < 8; ++s) {
                    const int ch = s*4 + (tid & 3);
                    const int h  = (nt % 3) * 4 + (ch >> 3);
                    const int d0 = (ch & 7) * 8;
                    *(f16x8*)(dst + ((size_t)(seq*NH + h)*P + hh*128 + r)*DH + d0) =
                        *(const f16x8*)&ep[r][ch*8];
                }
            } else {
                const int col = tid >> 1, rg = tid & 1;
                const int h = (nt % 3) * 4 + (col >> 6), d = col & 63;
                f16* drow = vt + ((size_t)(seq*NH + h)*DH + d)*P + hh*128 + rg*64;
                #pragma unroll
                for (int u = 0; u < 8; ++u) {
                    f16x8 vv;
                    #pragma unroll
                    for (int uu = 0; uu < 8; ++uu)
                        vv[uu] = ep[rg*64 + u*8 + uu][col];
                    *(f16x8*)(drow + u*8) = vv;
                }
            }
            __syncthreads();
        }
    }
    #undef BAR
    #undef LGKM
    #undef SCHB
}

// ---- attention (unchanged from passing round 5) ----
__global__ __launch_bounds__(512) void attn_kernel(
    const f16* __restrict__ q, const f16* __restrict__ k,
    const f16* __restrict__ vt, float* __restrict__ out)
{
    __shared__ __align__(16) char kl[32768];
    __shared__ __align__(16) char vl[32768];
    __shared__ __align__(16) char pl[8][2048];

    const int n = blockIdx.x;                    // 1536 = 8 * 192
    const int b = (n & 7) * 192 + (n >> 3);
    const int half = b & 1;
    const int head = (b >> 1) % NH;
    const int seq  = b / (2 * NH);

    const int tid  = threadIdx.x;
    const int lane = tid & 63;
    const int wave = tid >> 6;
    const int lr   = lane & 15;
    const int lg   = lane >> 4;

    const f16* qh = q  + (size_t)(seq*NH + head)*P*DH;
    const f16* kh = k  + (size_t)(seq*NH + head)*P*DH;
    const f16* vh = vt + (size_t)(seq*NH + head)*DH*P;

    {
        const int r0 = tid >> 3, ck = tid & 7;
        const int d0 = tid >> 5, cv = tid & 31;
        #pragma unroll
        for (int it = 0; it < 4; ++it) {
            const int row = it * 64 + r0;
            gload16(kh + row * 64 + ((ck ^ (row & 7)) * 8), kl + it * 8192 + tid * 16);
            const int d = it * 16 + d0;
            gload16(vh + d * 256 + (((cv & 24) | ((cv ^ d) & 7)) * 8), vl + it * 8192 + tid * 16);
        }
    }

    const int qr0 = half * 128 + wave * 16;
    const f16x8 aq0 = *(const f16x8*)(qh + (qr0 + lr) * DH + lg * 8);
    const f16x8 aq1 = *(const f16x8*)(qh + (qr0 + lr) * DH + 32 + lg * 8);

    __syncthreads();

    f32x4 s[16];
    #pragma unroll
    for (int t = 0; t < 16; ++t) s[t] = (f32x4){0.f,0.f,0.f,0.f};
    #pragma unroll
    for (int t = 0; t < 16; ++t) {
        const int row = t * 16 + lr;
        const f16x8 b0 = *(const f16x8*)(kl + row * 128 + ((lg ^ (row & 7)) * 16));
        const f16x8 b1 = *(const f16x8*)(kl + row * 128 + (((lg + 4) ^ (row & 7)) * 16));
        s[t] = MFMA16(aq0, b0, s[t]);
        s[t] = MFMA16(aq1, b1, s[t]);
    }

    float mx[4] = {-1e30f, -1e30f, -1e30f, -1e30f};
    #pragma unroll
    for (int t = 0; t < 16; ++t)
        #pragma unroll
        for (int i = 0; i < 4; ++i) mx[i] = fmaxf(mx[i], s[t][i]);
    #pragma unroll
    for (int st = 1; st < 16; st <<= 1)
        #pragma unroll
        for (int i = 0; i < 4; ++i) mx[i] = fmaxf(mx[i], __shfl_xor(mx[i], st));

    const float SCL = 0.125f * 1.44269504088896f;
    float rs[4] = {0.f, 0.f, 0.f, 0.f};
    #pragma unroll
    for (int t = 0; t < 16; ++t)
        #pragma unroll
        for (int i = 0; i < 4; ++i) {
            const float e = exp2f((s[t][i] - mx[i]) * SCL);
            s[t][i] = e;
            rs[i] += e;
        }
    #pragma unroll
    for (int st = 1; st < 16; st <<= 1)
        #pragma unroll
        for (int i = 0; i < 4; ++i) rs[i] += __shfl_xor(rs[i], st);

    char* pw = pl[wave];
    f32x4 o[4];
    #pragma unroll
    for (int t = 0; t < 4; ++t) o[t] = (f32x4){0.f,0.f,0.f,0.f};

    #pragma unroll
    for (int qq = 0; qq < 4; ++qq) {
        #pragma unroll
        for (int tt = 0; tt < 4; ++tt) {
            const int t = qq * 4 + tt;
            #pragma unroll
            for (int i = 0; i < 4; ++i) {
                const int r = lg * 4 + i;
                const int klocal = tt * 16 + lr;
                *(f16*)(pw + r * 128 + ((klocal * 2) ^ ((r & 7) << 4))) = (f16)s[t][i];
            }
        }
        #pragma unroll
        for (int kol = 0; kol < 2; ++kol) {
            const f16x8 ap = *(const f16x8*)(pw + lr * 128 + (((kol * 4 + lg) ^ (lr & 7)) * 16));
            #pragma unroll
            for (int dt = 0; dt < 4; ++dt) {
                const int row = dt * 16 + lr;
                const int ch  = qq * 8 + kol * 4 + lg;
                const f16x8 bv_ = *(const f16x8*)(vl + row * 512 + (((ch & 24) | ((ch ^ row) & 7)) * 16));
                o[dt] = MFMA16(ap, bv_, o[dt]);
            }
        }
    }

    #pragma unroll
    for (int i = 0; i < 4; ++i) rs[i] = 1.f / rs[i];
    float* op = out + ((size_t)seq * P + qr0) * DIMF + head * DH;
    #pragma unroll
    for (int t = 0; t < 4; ++t)
        #pragma unroll
        for (int i = 0; i < 4; ++i)
            op[(lg * 4 + i) * DIMF + t * 16 + lr] = o[t][i] * rs[i];
}

extern "C" void kernel_launch(void* const* d_in, const int* in_sizes, int n_in,
                              void* d_out, int out_size, void* d_ws, size_t ws_size,
                              hipStream_t stream) {
    const float* x  = (const float*)d_in[0];
    const float* Wq = (const float*)d_in[1];
    const float* bq = (const float*)d_in[2];
    const float* Wk = (const float*)d_in[3];
    const float* bk = (const float*)d_in[4];
    const float* Wv = (const float*)d_in[5];
    const float* bv = (const float*)d_in[6];
    float* out = (float*)d_out;

    f16* xh = (f16*)d_out;          // fp16 staging lives in d_out (fully consumed
    f16* wh = xh + XSZ;             // by proj_gemm before attn overwrites d_out)

    const size_t QSZ = (size_t)M * DIMF;
    f16* q  = (f16*)d_ws;
    f16* k  = q + QSZ;
    f16* vt = k + QSZ;

    const int convThreads = (int)((XSZ + 3 * WSZ) / 8);
    conv_kernel<<<convThreads / 256, 256, 0, stream>>>(x, Wq, Wk, Wv, xh, wh);
    proj_gemm<<<dim3(512), 512, 0, stream>>>(xh, wh, bq, bk, bv, q, k, vt);
    attn_kernel<<<dim3(NSEQ * NH * 2), 512, 0, stream>>>(q, k, vt, out);
}